// Round 2
// baseline (3576.810 us; speedup 1.0000x reference)
//
#include <hip/hip_runtime.h>
#include <hip/hip_bf16.h>

// Problem constants (fixed by the reference)
constexpr int NNODES = 200000;   // 4 graphs x 50000
constexpr int NGRAPH_NODES = 50000;
constexpr int NE = 3200000;
constexpr int H = 64;

// ---------------------------------------------------------------------------
// Fused 3-GEMM per inception block: Y = X@Wl + (Bl+B1+B2), S1 = X@W1, S2 = X@W2
// Block: 256 threads; 32 nodes per block staged in LDS.
// Thread (r=tid>>6, f=tid&63) accumulates 8 nodes x 3 matrices for feature f.
// LDS reads are wave-broadcast (same address across lanes) -> conflict-free.
// Safe in-place (X == Y): tile staged+synced before writes, no cross-block reads.
// ---------------------------------------------------------------------------
template <int DI>
__global__ __launch_bounds__(256) void gemm3_kernel(
    const float* __restrict__ X,
    const float* __restrict__ Wl, const float* __restrict__ Bl,
    const float* __restrict__ W1, const float* __restrict__ B1,
    const float* __restrict__ W2, const float* __restrict__ B2,
    float* __restrict__ Y, float* __restrict__ S1, float* __restrict__ S2)
{
    __shared__ float xs[32][DI];
    const int tid = threadIdx.x;
    const int f = tid & 63;
    const int r = tid >> 6;
    const int base = blockIdx.x * 32;

    // cooperative float4 stage of 32 rows
    const float4* xg = reinterpret_cast<const float4*>(X + (size_t)base * DI);
    float4* xsv = reinterpret_cast<float4*>(&xs[0][0]);
    constexpr int NV = 32 * DI / 4;
    #pragma unroll
    for (int i = tid; i < NV; i += 256) xsv[i] = xg[i];
    __syncthreads();

    float accL[8], acc1[8], acc2[8];
    #pragma unroll
    for (int i = 0; i < 8; ++i) { accL[i] = 0.f; acc1[i] = 0.f; acc2[i] = 0.f; }

    for (int k = 0; k < DI; ++k) {
        float wl = Wl[k * H + f];
        float w1 = W1[k * H + f];
        float w2 = W2[k * H + f];
        #pragma unroll
        for (int i = 0; i < 8; ++i) {
            float xv = xs[r * 8 + i][k];
            accL[i] = fmaf(xv, wl, accL[i]);
            acc1[i] = fmaf(xv, w1, acc1[i]);
            acc2[i] = fmaf(xv, w2, acc2[i]);
        }
    }

    float bias = Bl[f] + B1[f] + B2[f];
    #pragma unroll
    for (int i = 0; i < 8; ++i) {
        size_t n = (size_t)(base + r * 8 + i);
        Y[n * H + f]  = accL[i] + bias;
        S1[n * H + f] = acc1[i];
        S2[n * H + f] = acc2[i];
    }
}

// ---------------------------------------------------------------------------
// Block 3 GEMM (DI=64 -> DO=1): three dot products per node.
// ---------------------------------------------------------------------------
__global__ __launch_bounds__(256) void gemm3_out1_kernel(
    const float* __restrict__ X,
    const float* __restrict__ Wl, const float* __restrict__ Bl,
    const float* __restrict__ W1, const float* __restrict__ B1,
    const float* __restrict__ W2, const float* __restrict__ B2,
    float* __restrict__ Y, float* __restrict__ S1, float* __restrict__ S2)
{
    __shared__ float wls[64], w1s[64], w2s[64];
    const int tid = threadIdx.x;
    if (tid < 64) { wls[tid] = Wl[tid]; w1s[tid] = W1[tid]; w2s[tid] = W2[tid]; }
    __syncthreads();
    const int n = blockIdx.x * 256 + tid;
    if (n >= NNODES) return;
    const float4* xr = reinterpret_cast<const float4*>(X + (size_t)n * H);
    float aL = 0.f, a1 = 0.f, a2 = 0.f;
    #pragma unroll
    for (int kv = 0; kv < 16; ++kv) {
        float4 xv = xr[kv];
        int k = kv * 4;
        aL = fmaf(xv.x, wls[k + 0], aL); a1 = fmaf(xv.x, w1s[k + 0], a1); a2 = fmaf(xv.x, w2s[k + 0], a2);
        aL = fmaf(xv.y, wls[k + 1], aL); a1 = fmaf(xv.y, w1s[k + 1], a1); a2 = fmaf(xv.y, w2s[k + 1], a2);
        aL = fmaf(xv.z, wls[k + 2], aL); a1 = fmaf(xv.z, w1s[k + 2], a1); a2 = fmaf(xv.z, w2s[k + 2], a2);
        aL = fmaf(xv.w, wls[k + 3], aL); a1 = fmaf(xv.w, w1s[k + 3], a1); a2 = fmaf(xv.w, w2s[k + 3], a2);
    }
    float bias = Bl[0] + B1[0] + B2[0];
    Y[n] = aL + bias; S1[n] = a1; S2[n] = a2;
}

// ---------------------------------------------------------------------------
// 64-dim edge scatter: one wave per edge; lane = feature.
// Gather S[src] (coalesced 256B) and atomically add w*val into Y[dst].
// ---------------------------------------------------------------------------
__global__ __launch_bounds__(256) void scatter64_kernel(
    const int* __restrict__ EI, const float* __restrict__ EW,
    const float* __restrict__ S, float* __restrict__ Y)
{
    const int lane = threadIdx.x & 63;
    const int wid = (blockIdx.x * 256 + threadIdx.x) >> 6;
    const int nw = (gridDim.x * 256) >> 6;
    for (int e = wid; e < NE; e += nw) {
        int s = EI[e];
        int d = EI[NE + e];
        float w = EW[e];
        float v = S[(size_t)s * H + lane];
        unsafeAtomicAdd(&Y[(size_t)d * H + lane], w * v);
    }
}

// ---------------------------------------------------------------------------
// 1-dim edge scatter (block 3): one thread per edge.
// ---------------------------------------------------------------------------
__global__ __launch_bounds__(256) void scatter1_kernel(
    const int* __restrict__ EI, const float* __restrict__ EW,
    const float* __restrict__ S, float* __restrict__ Y)
{
    const int t = blockIdx.x * 256 + threadIdx.x;
    const int tot = gridDim.x * 256;
    for (int e = t; e < NE; e += tot) {
        int s = EI[e];
        int d = EI[NE + e];
        float w = EW[e];
        unsafeAtomicAdd(&Y[d], w * S[s]);
    }
}

// ---------------------------------------------------------------------------
// Readout: copy final x to both output slots, per-graph max via ordered-uint
// keys (monotone float->uint map handles negatives).
// ---------------------------------------------------------------------------
__device__ __forceinline__ unsigned fkey(float v) {
    unsigned u = __float_as_uint(v);
    return (u & 0x80000000u) ? ~u : (u | 0x80000000u);
}

__global__ __launch_bounds__(256) void readout_kernel(
    const float* __restrict__ Y3, float* __restrict__ body1,
    float* __restrict__ body2, unsigned int* __restrict__ keys)
{
    __shared__ unsigned int smax[4];
    const int tid = threadIdx.x;
    if (tid < 4) smax[tid] = 0u;
    __syncthreads();
    const int i = blockIdx.x * 256 + tid;
    if (i < NNODES) {
        float v = Y3[i];
        body1[i] = v;
        body2[i] = v;
        atomicMax(&smax[i / NGRAPH_NODES], fkey(v));
    }
    __syncthreads();
    if (tid < 4 && smax[tid]) atomicMax(&keys[tid], smax[tid]);
}

__global__ void finalize_kernel(const unsigned int* __restrict__ keys,
                                float* __restrict__ out)
{
    int i = threadIdx.x;
    if (i < 4) {
        unsigned k = keys[i];
        unsigned u = (k & 0x80000000u) ? (k ^ 0x80000000u) : ~k;
        out[i] = __uint_as_float(u);
    }
}

// ---------------------------------------------------------------------------
extern "C" void kernel_launch(void* const* d_in, const int* in_sizes, int n_in,
                              void* d_out, int out_size, void* d_ws, size_t ws_size,
                              hipStream_t stream)
{
    const float* x   = (const float*)d_in[0];
    const int*   ei  = (const int*)d_in[1];
    const float* ew  = (const float*)d_in[2];
    const int*   ei2 = (const int*)d_in[3];
    const float* ew2 = (const float*)d_in[4];
    // weights: 6..23  (per block: ln_w, ln_b, c1_w, c1_b, c2_w, c2_b)
    const float* W[18];
    for (int i = 0; i < 18; ++i) W[i] = (const float*)d_in[6 + i];

    float* Y  = (float*)d_ws;                       // 200000 x 64
    float* S1 = Y + (size_t)NNODES * H;             // 200000 x 64
    float* S2 = S1 + (size_t)NNODES * H;            // 200000 x 64
    float* Y3 = S2 + (size_t)NNODES * H;            // 200000
    unsigned int* keys = (unsigned int*)(Y3 + NNODES);  // 4

    float* out = (float*)d_out;   // [0..3]=graph max, [4..200003]=x, [200004..400003]=x

    hipMemsetAsync(keys, 0, 4 * sizeof(unsigned int), stream);

    // Block 1: DI=128
    gemm3_kernel<128><<<NNODES / 32, 256, 0, stream>>>(
        x, W[0], W[1], W[2], W[3], W[4], W[5], Y, S1, S2);
    scatter64_kernel<<<2048, 256, 0, stream>>>(ei,  ew,  S1, Y);
    scatter64_kernel<<<2048, 256, 0, stream>>>(ei2, ew2, S2, Y);

    // Block 2: DI=64 (in-place on Y)
    gemm3_kernel<64><<<NNODES / 32, 256, 0, stream>>>(
        Y, W[6], W[7], W[8], W[9], W[10], W[11], Y, S1, S2);
    scatter64_kernel<<<2048, 256, 0, stream>>>(ei,  ew,  S1, Y);
    scatter64_kernel<<<2048, 256, 0, stream>>>(ei2, ew2, S2, Y);

    // Block 3: DI=64 -> 1 (S1/S2 reused as [NNODES] scalars)
    gemm3_out1_kernel<<<(NNODES + 255) / 256, 256, 0, stream>>>(
        Y, W[12], W[13], W[14], W[15], W[16], W[17], Y3, S1, S2);
    scatter1_kernel<<<2048, 256, 0, stream>>>(ei,  ew,  S1, Y3);
    scatter1_kernel<<<2048, 256, 0, stream>>>(ei2, ew2, S2, Y3);

    // Readout
    readout_kernel<<<(NNODES + 255) / 256, 256, 0, stream>>>(
        Y3, out + 4, out + 4 + NNODES, keys);
    finalize_kernel<<<1, 64, 0, stream>>>(keys, out);
}